// Round 2
// baseline (33.971 us; speedup 1.0000x reference)
//
#include <hip/hip_runtime.h>
#include <stdint.h>
#include <string.h>
#include <math.h>

// RandomGate: output depends ONLY on jax.random.key(42) and dim=32768.
// Replicates JAX threefry streams under jax_threefry_partitionable=True
// (default since jax 0.4.36):
//   random_bits(key,32,shape)[e] = o0 ^ o1 of threefry2x32(key, hi=0, lo=e)
//   split(key,n)[i]              = (o0, o1) of threefry2x32(key, hi=0, lo=i)
// Float transforms (log/pow) are ulp-approximate; absorbed by the 2% absmax
// threshold (496.64 on a 24832 max bin).

#define DIM 32768
#define NCHAIN 48  // poisson Knuth subkey chain depth; P(need>48) ~ 0

struct Params {
  uint32_t kr0, kr1;            // k_rand
  uint32_t km0, km1;            // k_mult
  uint32_t sub0[NCHAIN];        // poisson subkey chain (host-precomputed)
  uint32_t sub1[NCHAIN];
  float    logp[8];             // log softmax-probs of power law
  int      invperm[8];          // inverse of jax.random.permutation(k_perm, 8)
};

__host__ __device__ static inline void tf2x32(uint32_t k0, uint32_t k1,
                                              uint32_t x0, uint32_t x1,
                                              uint32_t &o0, uint32_t &o1) {
  const uint32_t ks2 = 0x1BD11BDAu ^ k0 ^ k1;
  x0 += k0; x1 += k1;
#define RL(v,s) (((v) << (s)) | ((v) >> (32 - (s))))
#define RND(r) { x0 += x1; x1 = RL(x1, r); x1 ^= x0; }
  RND(13) RND(15) RND(26) RND(6)
  x0 += k1;  x1 += ks2 + 1u;
  RND(17) RND(29) RND(16) RND(24)
  x0 += ks2; x1 += k0 + 2u;
  RND(13) RND(15) RND(26) RND(6)
  x0 += k0;  x1 += k1 + 3u;
  RND(17) RND(29) RND(16) RND(24)
  x0 += k1;  x1 += ks2 + 4u;
  RND(13) RND(15) RND(26) RND(6)
  x0 += ks2; x1 += k0 + 5u;
#undef RND
#undef RL
  o0 = x0; o1 = x1;
}

// partitionable random_bits, 32-bit, flat element index e (size < 2^32)
__device__ static inline uint32_t rbits(uint32_t k0, uint32_t k1, uint32_t e) {
  uint32_t o0, o1;
  tf2x32(k0, k1, 0u, e, o0, o1);
  return o0 ^ o1;
}

__device__ static inline float u01(uint32_t bits) {
  return __uint_as_float((bits >> 9) | 0x3F800000u) - 1.0f;  // [0, 1)
}

__global__ void __launch_bounds__(128) zero8_kernel(int* __restrict__ out) {
  if (threadIdx.x < 8) out[threadIdx.x] = 0;
}

__global__ void __launch_bounds__(128)
gate_kernel(Params P, int* __restrict__ out) {
  __shared__ int hist[8];
  if (threadIdx.x < 8) hist[threadIdx.x] = 0;
  __syncthreads();

  const uint32_t row = blockIdx.x * 128u + threadIdx.x;
  const float TINY = 1.17549435e-38f;

  if (row < DIM) {
    // ---- random_matrix row: uniform(k_rand, (DIM, 8)) ----
    float rm[8];
#pragma unroll
    for (int j = 0; j < 8; ++j)
      rm[j] = u01(rbits(P.kr0, P.kr1, row * 8u + (uint32_t)j));

    // ---- categorical (gumbel argmax over (DIM,8,8)) + poisson per j ----
    int   bks[8];
    float pvs[8];
#pragma unroll
    for (int j = 0; j < 8; ++j) {
      int bestk = 0; float best = -3.0e38f;
#pragma unroll
      for (int kk = 0; kk < 8; ++kk) {
        uint32_t e = row * 64u + (uint32_t)(j * 8 + kk);
        float f = u01(rbits(P.km0, P.km1, e));
        float u = fmaxf(f, TINY);                 // uniform(minval=tiny)
        float g = -logf(-logf(u));                // gumbel
        float v = g + P.logp[kk];
        if (v > best) { best = v; bestk = kk; }
      }
      bks[j] = bestk;

      // lam = rm[bestk] without runtime indexing (rule #20)
      float lam = rm[0];
#pragma unroll
      for (int kk = 1; kk < 8; ++kk) lam = (bestk == kk) ? rm[kk] : lam;

      float pv;
      if (lam == 0.0f) {
        pv = 0.0f;                                // lax.select(lam==0, 0, ...)
      } else {
        // Knuth: k increments while log_prod > -lam; result = k - 1
        uint32_t e = row * 8u + (uint32_t)j;
        float lp = 0.0f; int kcnt = 0;
#pragma unroll 1
        for (int t = 0; t < NCHAIN; ++t) {
          if (!(lp > -lam)) break;
          ++kcnt;
          float u = u01(rbits(P.sub0[t], P.sub1[t], e));
          lp += logf(u);                          // logf(0) = -inf -> stops
        }
        pv = (float)(kcnt - 1);
      }
      pvs[j] = pv;
    }

    // ---- logits = zeros.at[row, sampled].set(pois): last-j wins;
    //      argmax(gates) == argmax(logits), first-occurrence ties ----
    int am = 0; float bv = -1.0f;
#pragma unroll
    for (int e2 = 0; e2 < 8; ++e2) {
      float v = 0.0f;
#pragma unroll
      for (int j = 0; j < 8; ++j) v = (bks[j] == e2) ? pvs[j] : v;
      if (v > bv) { bv = v; am = e2; }
    }
    atomicAdd(&hist[am], 1);
  }
  __syncthreads();
  if (threadIdx.x < 8)
    atomicAdd(&out[P.invperm[threadIdx.x]], hist[threadIdx.x]);
}

extern "C" void kernel_launch(void* const* d_in, const int* in_sizes, int n_in,
                              void* d_out, int out_size, void* d_ws, size_t ws_size,
                              hipStream_t stream) {
  (void)d_in; (void)in_sizes; (void)n_in; (void)d_ws; (void)ws_size; (void)out_size;

  Params P;

  // ---- key(42) = (0,42) -> split(key, 4), fold-like:
  //      child i = full output pair of threefry(key, 0, i) ----
  uint32_t c0[4], c1[4];
  for (uint32_t i = 0; i < 4; ++i)
    tf2x32(0u, 42u, 0u, i, c0[i], c1[i]);
  P.kr0 = c0[0]; P.kr1 = c1[0];          // k_rand
  P.km0 = c0[1]; P.km1 = c1[1];          // k_mult
  uint32_t kp0 = c0[2], kp1 = c1[2];     // k_pois
  uint32_t kq0 = c0[3], kq1 = c1[3];     // k_perm

  // ---- poisson Knuth subkey chain: rng, sub = split(rng) fold-like:
  //      new rng = TF(rng,0,0), subkey = TF(rng,0,1) ----
  {
    uint32_t r0 = kp0, r1 = kp1;
    for (int t = 0; t < NCHAIN; ++t) {
      uint32_t n0, n1, s0, s1;
      tf2x32(r0, r1, 0u, 0u, n0, n1);    // child 0 -> new rng
      tf2x32(r0, r1, 0u, 1u, s0, s1);    // child 1 -> subkey
      P.sub0[t] = s0; P.sub1[t] = s1;
      r0 = n0; r1 = n1;
    }
  }

  // ---- permutation(k_perm, 8): 1 round sort-by-random-bits ----
  {
    uint32_t s0, s1;
    tf2x32(kq0, kq1, 0u, 1u, s0, s1);    // _, subkey = split(k_perm)
    uint32_t sk[8];
    for (uint32_t i = 0; i < 8; ++i) {
      uint32_t a, b;
      tf2x32(s0, s1, 0u, i, a, b);
      sk[i] = a ^ b;                      // random_bits(subkey, 32, (8,))
    }
    int perm[8]; bool used[8] = {false,false,false,false,false,false,false,false};
    for (int pos = 0; pos < 8; ++pos) {  // stable argsort ascending (uint32)
      int best = -1;
      for (int i = 0; i < 8; ++i) {
        if (used[i]) continue;
        if (best < 0 || sk[i] < sk[best]) best = i;
      }
      used[best] = true; perm[pos] = best;
    }
    for (int i = 0; i < 8; ++i) P.invperm[perm[i]] = i;
  }

  // ---- logp: power-law softmax in f32, mirroring the reference ----
  {
    float exps[8], Z = 0.0f;
    for (int e = 0; e < 8; ++e) { exps[e] = powf((float)(e + 1), -3.0f); Z += exps[e]; }
    for (int e = 0; e < 8; ++e) P.logp[e] = logf(exps[e] / Z);
  }

  int* out = (int*)d_out;
  zero8_kernel<<<1, 128, 0, stream>>>(out);
  gate_kernel<<<DIM / 128, 128, 0, stream>>>(P, out);
}

// Round 3
// 16.605 us; speedup vs baseline: 2.0458x; 2.0458x over previous
//
#include <hip/hip_runtime.h>
#include <stdint.h>
#include <string.h>
#include <math.h>

// RandomGate: output depends ONLY on jax.random.key(42) and dim=32768.
// Exact replication of JAX partitionable threefry streams (verified round 2,
// absmax 0.0). This round: thread-per-(row,j) decomposition, single-log
// gumbel argmin transform, __logf fast log, LDS+ws partial histograms.

#define DIM    32768
#define NCHAIN 48   // poisson Knuth subkey chain depth; P(need>48) ~ 0
#define BLOCKS 1024 // DIM*8/256 threads, one per (row, j)

struct P1 {
  uint32_t kr0, kr1;            // k_rand
  uint32_t km0, km1;            // k_mult
  uint32_t sub0[NCHAIN];        // poisson subkey chain (host-precomputed)
  uint32_t sub1[NCHAIN];
  float    invp[8];             // 1 / p_k  (argmin w*invp == argmax logp+gumbel)
};
struct P2 { int invperm[8]; };  // inverse of jax.random.permutation(k_perm, 8)

__host__ __device__ static inline void tf2x32(uint32_t k0, uint32_t k1,
                                              uint32_t x0, uint32_t x1,
                                              uint32_t &o0, uint32_t &o1) {
  const uint32_t ks2 = 0x1BD11BDAu ^ k0 ^ k1;
  x0 += k0; x1 += k1;
#define RL(v,s) (((v) << (s)) | ((v) >> (32 - (s))))
#define RND(r) { x0 += x1; x1 = RL(x1, r); x1 ^= x0; }
  RND(13) RND(15) RND(26) RND(6)
  x0 += k1;  x1 += ks2 + 1u;
  RND(17) RND(29) RND(16) RND(24)
  x0 += ks2; x1 += k0 + 2u;
  RND(13) RND(15) RND(26) RND(6)
  x0 += k0;  x1 += k1 + 3u;
  RND(17) RND(29) RND(16) RND(24)
  x0 += k1;  x1 += ks2 + 4u;
  RND(13) RND(15) RND(26) RND(6)
  x0 += ks2; x1 += k0 + 5u;
#undef RND
#undef RL
  o0 = x0; o1 = x1;
}

// partitionable random_bits(key, 32, shape): element e -> xor of pair
__device__ static inline uint32_t rbits(uint32_t k0, uint32_t k1, uint32_t e) {
  uint32_t o0, o1;
  tf2x32(k0, k1, 0u, e, o0, o1);
  return o0 ^ o1;
}

__device__ static inline float u01(uint32_t bits) {
  return __uint_as_float((bits >> 9) | 0x3F800000u) - 1.0f;  // [0, 1)
}

__global__ void __launch_bounds__(256)
gate_kernel(P1 P, int* __restrict__ ws) {
  __shared__ int hist[8];
  if (threadIdx.x < 8) hist[threadIdx.x] = 0;
  __syncthreads();

  const uint32_t gid  = blockIdx.x * 256u + threadIdx.x;  // (row, j) flat
  const uint32_t row8 = gid & ~7u;                        // row * 8
  const int      j    = (int)(gid & 7u);
  const float TINY = 1.17549435e-38f;

  // ---- categorical: argmax_k (gumbel + logp_k) == argmin_k (-log u_k)/p_k ----
  int bestk = 0; float best = 3.0e38f;
#pragma unroll
  for (int kk = 0; kk < 8; ++kk) {
    float f = u01(rbits(P.km0, P.km1, gid * 8u + (uint32_t)kk));
    float u = fmaxf(f, TINY);            // uniform(minval=tiny)
    float w = -__logf(u);                // > 0
    float v = w * P.invp[kk];
    if (v < best) { best = v; bestk = kk; }
  }

  // ---- rate = random_matrix[row][bestk] (take_along_axis) ----
  float lam = u01(rbits(P.kr0, P.kr1, row8 + (uint32_t)bestk));

  // ---- poisson (Knuth): count iters while log_prod > -lam; result = cnt-1 ----
  int pvi = 0;
  if (lam > 0.0f) {
    float lp = 0.0f; int kcnt = 0;
#pragma unroll 1
    for (int t = 0; t < NCHAIN; ++t) {
      if (!(lp > -lam)) break;
      ++kcnt;
      lp += __logf(u01(rbits(P.sub0[t], P.sub1[t], gid)));  // log(0) = -inf stops
    }
    pvi = kcnt - 1;                      // in [0, 47]
  }

  // ---- combine the row's 8 lanes: logits.at[row, bk_j].set(pv_j), last j wins.
  //      Lane e2=j computes its own logit slot via 8 sub-wave shuffles. ----
  uint32_t packed = (uint32_t)bestk | ((uint32_t)pvi << 3);   // 9 bits
  int v = 0;                              // logits start at 0
#pragma unroll
  for (int jp = 0; jp < 8; ++jp) {
    uint32_t pk = __shfl(packed, jp, 8);
    v = ((int)(pk & 7u) == j) ? (int)(pk >> 3) : v;
  }
  // argmax over the 8 slots, first-occurrence tie-break (softmax is monotone)
  int am = j;
#pragma unroll
  for (int m = 1; m < 8; m <<= 1) {
    int ov = __shfl_xor(v,  m, 8);
    int oa = __shfl_xor(am, m, 8);
    if (ov > v || (ov == v && oa < am)) { v = ov; am = oa; }
  }
  if (j == 0) atomicAdd(&hist[am], 1);

  __syncthreads();
  if (threadIdx.x < 8) ws[blockIdx.x * 8 + threadIdx.x] = hist[threadIdx.x];
}

__global__ void __launch_bounds__(256)
reduce_kernel(P2 P, const int* __restrict__ ws, int* __restrict__ out) {
  __shared__ int part[256];
  const int t = threadIdx.x;
  const int col = t & 7, chunk = t >> 3;  // 32 chunks x 32 block-rows
  int s = 0;
#pragma unroll
  for (int r = 0; r < 32; ++r) s += ws[(chunk * 32 + r) * 8 + col];
  part[t] = s;
  __syncthreads();
  if (t < 8) {
    int tot = 0;
#pragma unroll
    for (int c = 0; c < 32; ++c) tot += part[c * 8 + t];
    out[P.invperm[t]] = tot;              // plain store: also zero-initializes
  }
}

extern "C" void kernel_launch(void* const* d_in, const int* in_sizes, int n_in,
                              void* d_out, int out_size, void* d_ws, size_t ws_size,
                              hipStream_t stream) {
  (void)d_in; (void)in_sizes; (void)n_in; (void)ws_size; (void)out_size;

  P1 P; P2 Q;

  // ---- key(42) = (0,42) -> split(key,4): child i = pair of TF(key, 0, i) ----
  uint32_t c0[4], c1[4];
  for (uint32_t i = 0; i < 4; ++i)
    tf2x32(0u, 42u, 0u, i, c0[i], c1[i]);
  P.kr0 = c0[0]; P.kr1 = c1[0];          // k_rand
  P.km0 = c0[1]; P.km1 = c1[1];          // k_mult
  uint32_t kp0 = c0[2], kp1 = c1[2];     // k_pois
  uint32_t kq0 = c0[3], kq1 = c1[3];     // k_perm

  // ---- poisson Knuth subkey chain: rng=TF(rng,0,0), sub=TF(rng,0,1) ----
  {
    uint32_t r0 = kp0, r1 = kp1;
    for (int t = 0; t < NCHAIN; ++t) {
      uint32_t n0, n1, s0, s1;
      tf2x32(r0, r1, 0u, 0u, n0, n1);
      tf2x32(r0, r1, 0u, 1u, s0, s1);
      P.sub0[t] = s0; P.sub1[t] = s1;
      r0 = n0; r1 = n1;
    }
  }

  // ---- permutation(k_perm, 8): argsort of random_bits(subkey, 32, (8,)) ----
  {
    uint32_t s0, s1;
    tf2x32(kq0, kq1, 0u, 1u, s0, s1);    // _, subkey = split(k_perm)
    uint32_t sk[8];
    for (uint32_t i = 0; i < 8; ++i) {
      uint32_t a, b;
      tf2x32(s0, s1, 0u, i, a, b);
      sk[i] = a ^ b;
    }
    int perm[8]; bool used[8] = {false,false,false,false,false,false,false,false};
    for (int pos = 0; pos < 8; ++pos) {  // stable argsort ascending
      int best = -1;
      for (int i = 0; i < 8; ++i) {
        if (used[i]) continue;
        if (best < 0 || sk[i] < sk[best]) best = i;
      }
      used[best] = true; perm[pos] = best;
    }
    for (int i = 0; i < 8; ++i) Q.invperm[perm[i]] = i;
  }

  // ---- invp: 1 / softmax(power-law), f32 mirroring the reference ----
  {
    float exps[8], Z = 0.0f;
    for (int e = 0; e < 8; ++e) { exps[e] = powf((float)(e + 1), -3.0f); Z += exps[e]; }
    for (int e = 0; e < 8; ++e) P.invp[e] = Z / exps[e];
  }

  int* out = (int*)d_out;
  int* ws  = (int*)d_ws;   // BLOCKS*8 ints = 32 KB
  gate_kernel<<<BLOCKS, 256, 0, stream>>>(P, ws);
  reduce_kernel<<<1, 256, 0, stream>>>(Q, ws, out);
}